// Round 1
// baseline (242.858 us; speedup 1.0000x reference)
//
#include <hip/hip_runtime.h>

#define T_   1024
#define B_   2
#define H_   16
#define DH   64
#define D_   1024
#define WND  32
#define KSZ  65
#define NG   32

typedef float f32x4 __attribute__((ext_vector_type(4)));
typedef __bf16 bf16x8 __attribute__((ext_vector_type(8)));
typedef unsigned short u16x4 __attribute__((ext_vector_type(4)));

__device__ __forceinline__ unsigned short f2bf(float f) {
  unsigned u = __float_as_uint(f);
  return (unsigned short)((u + 0x7fffu + ((u >> 16) & 1u)) >> 16);
}

// ---------------- convert x, Wq, Wk, Wv, Wo (f32) -> contiguous bf16 arena ----------------
__global__ __launch_bounds__(256) void cvt_kernel(const float* __restrict__ x,
    const float* __restrict__ wq, const float* __restrict__ wk,
    const float* __restrict__ wv, const float* __restrict__ wo,
    unsigned short* __restrict__ dst) {
  int i4 = blockIdx.x * 256 + threadIdx.x;
  if (i4 >= (6 * 1048576) / 4) return;
  int idx = i4 * 4;
  int r = idx >> 20;
  const float* src; int off;
  if (r < 2)       { src = x;  off = idx; }
  else if (r == 2) { src = wq; off = idx - 2 * 1048576; }
  else if (r == 3) { src = wk; off = idx - 3 * 1048576; }
  else if (r == 4) { src = wv; off = idx - 4 * 1048576; }
  else             { src = wo; off = idx - 5 * 1048576; }
  f32x4 v = *(const f32x4*)(src + off);
  u16x4 o;
  o.x = f2bf(v[0]); o.y = f2bf(v[1]); o.z = f2bf(v[2]); o.w = f2bf(v[3]);
  *(u16x4*)(dst + idx) = o;
}

// ---------------- stable "argsort(!mask)" -> first NG indices per batch ----------------
__global__ void gidx_kernel(const int* __restrict__ mask, int* __restrict__ gidx,
                            float* __restrict__ gval) {
  int b = blockIdx.x;
  if (threadIdx.x != 0) return;
  int cnt = 0;
  for (int t = 0; t < T_ && cnt < NG; ++t)
    if (mask[b * T_ + t] != 0) { gidx[b * NG + cnt] = t; gval[b * NG + cnt] = 1.f; ++cnt; }
  for (int t = 0; t < T_ && cnt < NG; ++t)
    if (mask[b * T_ + t] == 0) { gidx[b * NG + cnt] = t; gval[b * NG + cnt] = 0.f; ++cnt; }
}

// ---------------- bf16 MFMA GEMM: C = A (MxK) * B^T (NxK), K=1024, BN=128 ----------------
// MODE 0: z-indexed QKV, C written in (b,h,t,d) f32 layout. MODE 1: plain row-major f32.
template<int MODE, int BM>
__global__ __launch_bounds__(256) void gemm128(const unsigned short* __restrict__ A,
    const unsigned short* __restrict__ B0, const unsigned short* __restrict__ B1,
    const unsigned short* __restrict__ B2,
    float* __restrict__ C0, float* __restrict__ C1, float* __restrict__ C2) {
  constexpr int K = 1024;
  constexpr int FM = BM / 32;        // 16-row fragments per wave (m dim)
  constexpr int ACH = BM * 8 / 256;  // A 16B-chunks per thread per K-step
  constexpr int WM = BM / 2;         // wave tile rows
  __shared__ __attribute__((aligned(16))) unsigned short As[BM * 64];
  __shared__ __attribute__((aligned(16))) unsigned short Bs[128 * 64];

  int m0 = blockIdx.x * BM, n0 = blockIdx.y * 128;
  const unsigned short* Bm; float* C;
  if (MODE == 0) {
    int zz = blockIdx.z;
    Bm = (zz == 0) ? B0 : ((zz == 1) ? B1 : B2);
    C  = (zz == 0) ? C0 : ((zz == 1) ? C1 : C2);
  } else { Bm = B0; C = C0; }

  int tid = threadIdx.x;
  int w = tid >> 6, l = tid & 63;
  int wr = w >> 1, wc = w & 1;
  int lr = l & 15, kg = l >> 4;

  f32x4 acc[FM][4] = {};

  for (int kt = 0; kt < K; kt += 64) {
    __syncthreads();
#pragma unroll
    for (int i = 0; i < ACH; ++i) {
      int ci = tid + 256 * i;
      int row = ci >> 3, c8 = ci & 7;
      *(bf16x8*)&As[row * 64 + ((c8 ^ (row & 7)) * 8)] =
          *(const bf16x8*)&A[(size_t)(m0 + row) * K + kt + c8 * 8];
    }
#pragma unroll
    for (int i = 0; i < 4; ++i) {
      int ci = tid + 256 * i;
      int row = ci >> 3, c8 = ci & 7;
      *(bf16x8*)&Bs[row * 64 + ((c8 ^ (row & 7)) * 8)] =
          *(const bf16x8*)&Bm[(size_t)(n0 + row) * K + kt + c8 * 8];
    }
    __syncthreads();
#pragma unroll
    for (int kk = 0; kk < 2; ++kk) {
      int c8 = kk * 4 + kg;
      bf16x8 af[FM], bfr[4];
#pragma unroll
      for (int mi = 0; mi < FM; ++mi) {
        int row = wr * WM + mi * 16 + lr;
        af[mi] = *(bf16x8*)&As[row * 64 + ((c8 ^ (row & 7)) * 8)];
      }
#pragma unroll
      for (int ni = 0; ni < 4; ++ni) {
        int row = wc * 64 + ni * 16 + lr;
        bfr[ni] = *(bf16x8*)&Bs[row * 64 + ((c8 ^ (row & 7)) * 8)];
      }
#pragma unroll
      for (int mi = 0; mi < FM; ++mi)
#pragma unroll
        for (int ni = 0; ni < 4; ++ni)
          acc[mi][ni] = __builtin_amdgcn_mfma_f32_16x16x32_bf16(af[mi], bfr[ni], acc[mi][ni], 0, 0, 0);
    }
  }

#pragma unroll
  for (int mi = 0; mi < FM; ++mi) {
#pragma unroll
    for (int ni = 0; ni < 4; ++ni) {
      int mbase = m0 + wr * WM + mi * 16 + (l >> 4) * 4;
      int n = n0 + wc * 64 + ni * 16 + (l & 15);
#pragma unroll
      for (int r = 0; r < 4; ++r) {
        int m = mbase + r;
        float val = acc[mi][ni][r];
        if (MODE == 0) {
          int b = m >> 10, t = m & 1023, h = n >> 6, d = n & 63;
          C[(((size_t)(b * H_ + h) * T_) + t) * DH + d] = val;
        } else {
          C[(size_t)m * 1024 + n] = val;
        }
      }
    }
  }
}

// ---------------- attention core: scores, dual softmax, ctx, full_attn rows ----------------
__global__ __launch_bounds__(256) void attn_kernel(
    const float* __restrict__ qf, const float* __restrict__ kf, const float* __restrict__ vf,
    const int* __restrict__ gidx_g, const float* __restrict__ gval_g,
    unsigned short* __restrict__ ctxb, float* __restrict__ fa) {
  int tid = threadIdx.x;
  int t0 = blockIdx.x * 32;
  int h = blockIdx.y, b = blockIdx.z;

  __shared__ __attribute__((aligned(16))) float Qs[32][64];
  __shared__ __attribute__((aligned(16))) float Ka[128][68];  // 0..95 window, 96..127 globals
  __shared__ __attribute__((aligned(16))) float Va[128][64];
  __shared__ __attribute__((aligned(16))) float Sw[32][104];  // raw scores -> w_out
  __shared__ float m_out_s[32], invdo_s[32], rowfac_s[32];
  __shared__ short gmap[1024];
  __shared__ int   gidx_s[32];
  __shared__ float gval_s[32];

  if (tid < 32) { gidx_s[tid] = gidx_g[b * NG + tid]; gval_s[tid] = gval_g[b * NG + tid]; }
#pragma unroll
  for (int i = 0; i < 4; ++i) gmap[tid * 4 + i] = -1;
  __syncthreads();
  if (tid < 32 && gval_s[tid] > 0.f) gmap[gidx_s[tid]] = (short)tid;

  const float* qbh = qf + (size_t)(b * H_ + h) * T_ * DH;
  const float* kbh = kf + (size_t)(b * H_ + h) * T_ * DH;
  const float* vbh = vf + (size_t)(b * H_ + h) * T_ * DH;

  for (int fi = tid; fi < 32 * 16; fi += 256) {
    int r = fi >> 4, c4 = (fi & 15) * 4;
    *(f32x4*)&Qs[r][c4] = *(const f32x4*)(qbh + (t0 + r) * DH + c4);
  }
  for (int fi = tid; fi < 96 * 16; fi += 256) {
    int r = fi >> 4, c4 = (fi & 15) * 4;
    int col = t0 - 32 + r;
    f32x4 kv = {0.f, 0.f, 0.f, 0.f}, vv = {0.f, 0.f, 0.f, 0.f};
    if (col >= 0 && col < T_) {
      kv = *(const f32x4*)(kbh + col * DH + c4);
      vv = *(const f32x4*)(vbh + col * DH + c4);
    }
    *(f32x4*)&Ka[r][c4] = kv;
    *(f32x4*)&Va[r][c4] = vv;
  }
  for (int fi = tid; fi < 32 * 16; fi += 256) {
    int g = fi >> 4, c4 = (fi & 15) * 4;
    f32x4 kv = {0.f, 0.f, 0.f, 0.f}, vv = {0.f, 0.f, 0.f, 0.f};
    if (gval_s[g] > 0.f) {
      int col = gidx_s[g];
      kv = *(const f32x4*)(kbh + col * DH + c4);
      vv = *(const f32x4*)(vbh + col * DH + c4);
    }
    *(f32x4*)&Ka[96 + g][c4] = kv;
    *(f32x4*)&Va[96 + g][c4] = vv;
  }
  __syncthreads();

  // phase 1: raw scores (pad slots naturally 0; invalid globals -1e9)
  const float scale = 0.125f;
  for (int idx = tid; idx < 32 * 97; idx += 256) {
    int t = idx / 97;
    int j = idx - t * 97;
    int row = (j < KSZ) ? (t + j) : (j + 31);  // 96 + (j - 65)
    float s = 0.f;
#pragma unroll
    for (int d = 0; d < 64; d += 4) {
      f32x4 qv = *(f32x4*)&Qs[t][d];
      f32x4 kv = *(f32x4*)&Ka[row][d];
      s += qv[0] * kv[0] + qv[1] * kv[1] + qv[2] * kv[2] + qv[3] * kv[3];
    }
    s *= scale;
    if (j >= KSZ && !(gval_s[j - KSZ] > 0.f)) s = -1e9f;
    Sw[t][j] = s;
  }
  __syncthreads();

  // phase 2: per-row stats for BOTH softmaxes (8 threads per row)
  {
    int r = tid >> 3, lg = tid & 7;
    int t_abs = t0 + r;
    int left = (t_abs - WND > 0) ? (t_abs - WND) : 0;
    int tmp = t_abs + WND + 1; if (tmp > T_) tmp = T_;
    int wl = tmp - left;  // dense-valid local slots: jj < wl
    float mo = -1e30f, md = -1e30f;
    for (int j = lg; j < 97; j += 8) {
      float s = Sw[r][j];
      mo = fmaxf(mo, s);
      bool vd = (j < KSZ) ? (j < wl) : true;
      if (vd) md = fmaxf(md, s);
    }
#pragma unroll
    for (int o = 1; o < 8; o <<= 1) {
      mo = fmaxf(mo, __shfl_xor(mo, o));
      md = fmaxf(md, __shfl_xor(md, o));
    }
    float eo = 0.f, ed = 0.f;
    for (int j = lg; j < 97; j += 8) {
      float s = Sw[r][j];
      eo += __expf(s - mo);
      bool vd = (j < KSZ) ? (j < wl) : true;
      if (vd) ed += __expf(s - md);
    }
#pragma unroll
    for (int o = 1; o < 8; o <<= 1) {
      eo += __shfl_xor(eo, o);
      ed += __shfl_xor(ed, o);
    }
    if (lg == 0) {
      m_out_s[r] = mo;
      invdo_s[r] = 1.f / eo;
      rowfac_s[r] = (eo / ed) * __expf(mo - md);  // w_dense = w_out * rowfac (valid slots)
    }
  }
  __syncthreads();

  // phase 2b: scores -> out-path weights in place
  for (int idx = tid; idx < 32 * 97; idx += 256) {
    int t = idx / 97;
    int j = idx - t * 97;
    Sw[t][j] = __expf(Sw[t][j] - m_out_s[t]) * invdo_s[t];
  }
  __syncthreads();

  // phase 3: ctx = w_out · V  (pad/invalid V rows are zero)
  for (int p = 0; p < 2; ++p) {
    int t = (tid >> 4) + p * 16;
    int d4 = (tid & 15) * 4;
    f32x4 acc = {0.f, 0.f, 0.f, 0.f};
    for (int j = 0; j < KSZ; ++j) {
      float wgt = Sw[t][j];
      f32x4 vv = *(f32x4*)&Va[t + j][d4];
      acc += wgt * vv;
    }
#pragma unroll 4
    for (int g = 0; g < NG; ++g) {
      float wgt = Sw[t][KSZ + g];
      f32x4 vv = *(f32x4*)&Va[96 + g][d4];
      acc += wgt * vv;
    }
    size_t cbase = ((size_t)(b * T_ + t0 + t)) * D_ + h * DH + d4;
    u16x4 st;
    st.x = f2bf(acc[0]); st.y = f2bf(acc[1]); st.z = f2bf(acc[2]); st.w = f2bf(acc[3]);
    *(u16x4*)(ctxb + cbase) = st;
  }

  // phase 4: stream full_attn rows (band @ col=left+jj gated by jj<wl, + globals via gmap)
  for (int r = 0; r < 32; ++r) {
    int t_abs = t0 + r;
    int left = (t_abs - WND > 0) ? (t_abs - WND) : 0;
    int tmp = t_abs + WND + 1; if (tmp > T_) tmp = T_;
    int wl = tmp - left;
    float rf = rowfac_s[r];
    float* dst = fa + (((size_t)(b * H_ + h) * T_) + t_abs) * T_;
    int c0 = tid * 4;
    f32x4 o;
#pragma unroll
    for (int e = 0; e < 4; ++e) {
      int c = c0 + e;
      float wv = 0.f;
      int jj = c - left;
      if (jj >= 0 && jj < wl) wv = Sw[r][jj] * rf;
      int g = gmap[c];
      if (g >= 0) wv += Sw[r][KSZ + g] * rf;
      o[e] = wv;
    }
    *(f32x4*)(dst + c0) = o;
  }
}

extern "C" void kernel_launch(void* const* d_in, const int* in_sizes, int n_in,
                              void* d_out, int out_size, void* d_ws, size_t ws_size,
                              hipStream_t stream) {
  const float* x   = (const float*)d_in[0];
  const int* gmask = (const int*)d_in[1];
  const float* wq  = (const float*)d_in[2];
  const float* wk  = (const float*)d_in[3];
  const float* wv  = (const float*)d_in[4];
  const float* wo  = (const float*)d_in[5];
  // d_in[6] = maxG (constant 32, compiled in)

  char* ws = (char*)d_ws;
  unsigned short* bfarena = (unsigned short*)ws;     // 6M bf16: x(2M) Wq Wk Wv Wo (1M each)
  unsigned short* xb  = bfarena;
  unsigned short* wqb = bfarena + 2 * 1048576;
  unsigned short* wkb = bfarena + 3 * 1048576;
  unsigned short* wvb = bfarena + 4 * 1048576;
  unsigned short* wob = bfarena + 5 * 1048576;
  float* qf = (float*)(ws + 12582912);
  float* kf = qf + 2097152;
  float* vf = kf + 2097152;
  unsigned short* ctxb = (unsigned short*)(vf + 2097152);
  int*   gidx = (int*)(ctxb + 2097152);
  float* gval = (float*)(gidx + 64);

  float* outp = (float*)d_out;
  float* fa   = outp + 2097152;

  cvt_kernel<<<dim3(6144), dim3(256), 0, stream>>>(x, wq, wk, wv, wo, bfarena);
  gidx_kernel<<<dim3(2), dim3(64), 0, stream>>>(gmask, gidx, gval);
  gemm128<0, 128><<<dim3(16, 8, 3), dim3(256), 0, stream>>>(xb, wqb, wkb, wvb, qf, kf, vf);
  attn_kernel<<<dim3(32, 16, 2), dim3(256), 0, stream>>>(qf, kf, vf, gidx, gval, ctxb, fa);
  gemm128<1, 64><<<dim3(32, 8, 1), dim3(256), 0, stream>>>(ctxb, wob, wob, wob, outp, outp, outp);
}

// Round 2
// 119.596 us; speedup vs baseline: 2.0307x; 2.0307x over previous
//
#include <hip/hip_runtime.h>

#define T_   1024
#define B_   2
#define H_   16
#define DH   64
#define D_   1024
#define WND  32
#define KSZ  65
#define NG   32

typedef float f32x4 __attribute__((ext_vector_type(4)));
typedef __bf16 bf16x8 __attribute__((ext_vector_type(8)));
typedef unsigned short u16x4 __attribute__((ext_vector_type(4)));

__device__ __forceinline__ unsigned short f2bf(float f) {
  unsigned u = __float_as_uint(f);
  return (unsigned short)((u + 0x7fffu + ((u >> 16) & 1u)) >> 16);
}
__device__ __forceinline__ float bf2f(unsigned short s) {
  return __uint_as_float(((unsigned)s) << 16);
}

// ---------------- convert x, Wq, Wk, Wv, Wo (f32) -> contiguous bf16 arena ----------------
__global__ __launch_bounds__(256) void cvt_kernel(const float* __restrict__ x,
    const float* __restrict__ wq, const float* __restrict__ wk,
    const float* __restrict__ wv, const float* __restrict__ wo,
    unsigned short* __restrict__ dst) {
  int i4 = blockIdx.x * 256 + threadIdx.x;
  if (i4 >= (6 * 1048576) / 4) return;
  int idx = i4 * 4;
  int r = idx >> 20;
  const float* src; int off;
  if (r < 2)       { src = x;  off = idx; }
  else if (r == 2) { src = wq; off = idx - 2 * 1048576; }
  else if (r == 3) { src = wk; off = idx - 3 * 1048576; }
  else if (r == 4) { src = wv; off = idx - 4 * 1048576; }
  else             { src = wo; off = idx - 5 * 1048576; }
  f32x4 v = *(const f32x4*)(src + off);
  u16x4 o;
  o.x = f2bf(v[0]); o.y = f2bf(v[1]); o.z = f2bf(v[2]); o.w = f2bf(v[3]);
  *(u16x4*)(dst + idx) = o;
}

// ---------------- stable "argsort(!mask)" first NG indices: 1-wave ballot scan ----------------
__global__ void gidx_kernel(const int* __restrict__ mask, int* __restrict__ gidx,
                            float* __restrict__ gval) {
  int b = blockIdx.x;
  int lane = threadIdx.x;  // 64 lanes
  const int* mb = mask + b * T_;
  unsigned long long lanemask = (1ull << lane) - 1ull;
  int base = 0;
  for (int c = 0; c < 16; ++c) {
    int t = c * 64 + lane;
    bool m = mb[t] != 0;
    unsigned long long bal = __ballot(m);
    int rank = __popcll(bal & lanemask);
    if (m && base + rank < NG) { gidx[b * NG + base + rank] = t; gval[b * NG + base + rank] = 1.f; }
    base += __popcll(bal);
    if (base >= NG) break;
  }
  int start = base < NG ? base : NG;
  if (start < NG) {
    base = start;
    for (int c = 0; c < 16; ++c) {
      int t = c * 64 + lane;
      bool m = mb[t] == 0;
      unsigned long long bal = __ballot(m);
      int rank = __popcll(bal & lanemask);
      if (m && base + rank < NG) { gidx[b * NG + base + rank] = t; gval[b * NG + base + rank] = 0.f; }
      base += __popcll(bal);
      if (base >= NG) break;
    }
  }
}

// ---------------- bf16 MFMA GEMM: C = A (MxK) * B^T (NxK), K=1024, BN=128 ----------------
template<int MODE, int BM>
__global__ __launch_bounds__(256) void gemm128(const unsigned short* __restrict__ A,
    const unsigned short* __restrict__ B0, const unsigned short* __restrict__ B1,
    const unsigned short* __restrict__ B2,
    float* __restrict__ C0, float* __restrict__ C1, float* __restrict__ C2) {
  constexpr int K = 1024;
  constexpr int FM = BM / 32;
  constexpr int ACH = BM * 8 / 256;
  constexpr int WM = BM / 2;
  __shared__ __attribute__((aligned(16))) unsigned short As[BM * 64];
  __shared__ __attribute__((aligned(16))) unsigned short Bs[128 * 64];

  int m0 = blockIdx.x * BM, n0 = blockIdx.y * 128;
  const unsigned short* Bm; float* C;
  if (MODE == 0) {
    int zz = blockIdx.z;
    Bm = (zz == 0) ? B0 : ((zz == 1) ? B1 : B2);
    C  = (zz == 0) ? C0 : ((zz == 1) ? C1 : C2);
  } else { Bm = B0; C = C0; }

  int tid = threadIdx.x;
  int w = tid >> 6, l = tid & 63;
  int wr = w >> 1, wc = w & 1;
  int lr = l & 15, kg = l >> 4;

  f32x4 acc[FM][4] = {};

  for (int kt = 0; kt < K; kt += 64) {
    __syncthreads();
#pragma unroll
    for (int i = 0; i < ACH; ++i) {
      int ci = tid + 256 * i;
      int row = ci >> 3, c8 = ci & 7;
      *(bf16x8*)&As[row * 64 + ((c8 ^ (row & 7)) * 8)] =
          *(const bf16x8*)&A[(size_t)(m0 + row) * K + kt + c8 * 8];
    }
#pragma unroll
    for (int i = 0; i < 4; ++i) {
      int ci = tid + 256 * i;
      int row = ci >> 3, c8 = ci & 7;
      *(bf16x8*)&Bs[row * 64 + ((c8 ^ (row & 7)) * 8)] =
          *(const bf16x8*)&Bm[(size_t)(n0 + row) * K + kt + c8 * 8];
    }
    __syncthreads();
#pragma unroll
    for (int kk = 0; kk < 2; ++kk) {
      int c8 = kk * 4 + kg;
      bf16x8 af[FM], bfr[4];
#pragma unroll
      for (int mi = 0; mi < FM; ++mi) {
        int row = wr * WM + mi * 16 + lr;
        af[mi] = *(bf16x8*)&As[row * 64 + ((c8 ^ (row & 7)) * 8)];
      }
#pragma unroll
      for (int ni = 0; ni < 4; ++ni) {
        int row = wc * 64 + ni * 16 + lr;
        bfr[ni] = *(bf16x8*)&Bs[row * 64 + ((c8 ^ (row & 7)) * 8)];
      }
#pragma unroll
      for (int mi = 0; mi < FM; ++mi)
#pragma unroll
        for (int ni = 0; ni < 4; ++ni)
          acc[mi][ni] = __builtin_amdgcn_mfma_f32_16x16x32_bf16(af[mi], bfr[ni], acc[mi][ni], 0, 0, 0);
    }
  }

#pragma unroll
  for (int mi = 0; mi < FM; ++mi) {
#pragma unroll
    for (int ni = 0; ni < 4; ++ni) {
      int mbase = m0 + wr * WM + mi * 16 + (l >> 4) * 4;
      int n = n0 + wc * 64 + ni * 16 + (l & 15);
#pragma unroll
      for (int r = 0; r < 4; ++r) {
        int m = mbase + r;
        float val = acc[mi][ni][r];
        if (MODE == 0) {
          int b = m >> 10, t = m & 1023, h = n >> 6, d = n & 63;
          C[(((size_t)(b * H_ + h) * T_) + t) * DH + d] = val;
        } else {
          C[(size_t)m * 1024 + n] = val;
        }
      }
    }
  }
}

// ---------------- attention core (512 threads, 72.6KB LDS -> 2 blocks/CU) ----------------
__global__ __launch_bounds__(512, 4) void attn_kernel(
    const float* __restrict__ qf, const float* __restrict__ kf, const float* __restrict__ vf,
    const int* __restrict__ gidx_g, const float* __restrict__ gval_g,
    unsigned short* __restrict__ ctxb, float* __restrict__ fa) {
  int tid = threadIdx.x;
  int t0 = blockIdx.x * 32;
  int h = blockIdx.y, b = blockIdx.z;

  __shared__ __attribute__((aligned(16))) float Qs[32][64];
  __shared__ __attribute__((aligned(16))) float Ka[128][68];          // f32 K: 0..95 window, 96..127 globals
  __shared__ __attribute__((aligned(16))) unsigned short Vb[128][68]; // bf16 V
  __shared__ __attribute__((aligned(16))) float Sw[32][104];          // raw scores -> w_out
  __shared__ float m_out_s[32], invdo_s[32], rowfac_s[32];
  __shared__ int   gidx_s[32];
  __shared__ float gval_s[32];

  if (tid < 32) { gidx_s[tid] = gidx_g[b * NG + tid]; gval_s[tid] = gval_g[b * NG + tid]; }
  __syncthreads();

  const float* qbh = qf + (size_t)(b * H_ + h) * T_ * DH;
  const float* kbh = kf + (size_t)(b * H_ + h) * T_ * DH;
  const float* vbh = vf + (size_t)(b * H_ + h) * T_ * DH;

  {  // Q stage: exactly 512 items
    int r = tid >> 4, c4 = (tid & 15) * 4;
    *(f32x4*)&Qs[r][c4] = *(const f32x4*)(qbh + (t0 + r) * DH + c4);
  }
#pragma unroll
  for (int it = 0; it < 3; ++it) {  // window K/V: 96*16 items
    int fi = tid + it * 512;
    int r = fi >> 4, c4 = (fi & 15) * 4;
    int col = t0 - 32 + r;
    f32x4 kv = {0.f, 0.f, 0.f, 0.f}, vv = {0.f, 0.f, 0.f, 0.f};
    if (col >= 0 && col < T_) {
      kv = *(const f32x4*)(kbh + col * DH + c4);
      vv = *(const f32x4*)(vbh + col * DH + c4);
    }
    *(f32x4*)&Ka[r][c4] = kv;
    u16x4 vb; vb.x = f2bf(vv[0]); vb.y = f2bf(vv[1]); vb.z = f2bf(vv[2]); vb.w = f2bf(vv[3]);
    *(u16x4*)&Vb[r][c4] = vb;
  }
  {  // globals: 32*16 = 512 items
    int g = tid >> 4, c4 = (tid & 15) * 4;
    f32x4 kv = {0.f, 0.f, 0.f, 0.f}, vv = {0.f, 0.f, 0.f, 0.f};
    if (gval_s[g] > 0.f) {
      int col = gidx_s[g];
      kv = *(const f32x4*)(kbh + col * DH + c4);
      vv = *(const f32x4*)(vbh + col * DH + c4);
    }
    *(f32x4*)&Ka[96 + g][c4] = kv;
    u16x4 vb; vb.x = f2bf(vv[0]); vb.y = f2bf(vv[1]); vb.z = f2bf(vv[2]); vb.w = f2bf(vv[3]);
    *(u16x4*)&Vb[96 + g][c4] = vb;
  }
  __syncthreads();

  // phase 1: raw scores (pad slots naturally 0; invalid globals -1e9)
  const float scale = 0.125f;
  for (int idx = tid; idx < 32 * 97; idx += 512) {
    int t = idx / 97;
    int j = idx - t * 97;
    int row = (j < KSZ) ? (t + j) : (j + 31);
    float s = 0.f;
#pragma unroll
    for (int d = 0; d < 64; d += 4) {
      f32x4 qv = *(f32x4*)&Qs[t][d];
      f32x4 kv = *(f32x4*)&Ka[row][d];
      s += qv[0] * kv[0] + qv[1] * kv[1] + qv[2] * kv[2] + qv[3] * kv[3];
    }
    s *= scale;
    if (j >= KSZ && !(gval_s[j - KSZ] > 0.f)) s = -1e9f;
    Sw[t][j] = s;
  }
  __syncthreads();

  // phase 2: per-row stats for BOTH softmaxes (16 lanes per row)
  {
    int r = tid >> 4, lg = tid & 15;
    int t_abs = t0 + r;
    int left = (t_abs - WND > 0) ? (t_abs - WND) : 0;
    int tmp = t_abs + WND + 1; if (tmp > T_) tmp = T_;
    int wl = tmp - left;
    float mo = -1e30f, md = -1e30f;
    for (int j = lg; j < 97; j += 16) {
      float s = Sw[r][j];
      mo = fmaxf(mo, s);
      bool vd = (j < KSZ) ? (j < wl) : true;
      if (vd) md = fmaxf(md, s);
    }
#pragma unroll
    for (int o = 1; o < 16; o <<= 1) {
      mo = fmaxf(mo, __shfl_xor(mo, o, 16));
      md = fmaxf(md, __shfl_xor(md, o, 16));
    }
    float eo = 0.f, ed = 0.f;
    for (int j = lg; j < 97; j += 16) {
      float s = Sw[r][j];
      eo += __expf(s - mo);
      bool vd = (j < KSZ) ? (j < wl) : true;
      if (vd) ed += __expf(s - md);
    }
#pragma unroll
    for (int o = 1; o < 16; o <<= 1) {
      eo += __shfl_xor(eo, o, 16);
      ed += __shfl_xor(ed, o, 16);
    }
    if (lg == 0) {
      m_out_s[r] = mo;
      invdo_s[r] = 1.f / eo;
      rowfac_s[r] = (eo / ed) * __expf(mo - md);
    }
  }
  __syncthreads();

  // phase 2b: scores -> out-path weights in place
  for (int idx = tid; idx < 32 * 97; idx += 512) {
    int t = idx / 97;
    int j = idx - t * 97;
    Sw[t][j] = __expf(Sw[t][j] - m_out_s[t]) * invdo_s[t];
  }
  __syncthreads();

  // phase 3: ctx = w_out · V  (exactly 512 work units)
  {
    int t = tid >> 4;
    int d4 = (tid & 15) * 4;
    f32x4 acc = {0.f, 0.f, 0.f, 0.f};
#pragma unroll 4
    for (int j = 0; j < KSZ; ++j) {
      float wgt = Sw[t][j];
      u16x4 raw = *(u16x4*)&Vb[t + j][d4];
      acc[0] += wgt * bf2f(raw.x);
      acc[1] += wgt * bf2f(raw.y);
      acc[2] += wgt * bf2f(raw.z);
      acc[3] += wgt * bf2f(raw.w);
    }
#pragma unroll 4
    for (int g = 0; g < NG; ++g) {
      float wgt = Sw[t][KSZ + g];
      u16x4 raw = *(u16x4*)&Vb[96 + g][d4];
      acc[0] += wgt * bf2f(raw.x);
      acc[1] += wgt * bf2f(raw.y);
      acc[2] += wgt * bf2f(raw.z);
      acc[3] += wgt * bf2f(raw.w);
    }
    size_t cbase = ((size_t)(b * T_ + t0 + t)) * D_ + h * DH + d4;
    u16x4 st;
    st.x = f2bf(acc[0]); st.y = f2bf(acc[1]); st.z = f2bf(acc[2]); st.w = f2bf(acc[3]);
    *(u16x4*)(ctxb + cbase) = st;
  }

  // phase 4: dense full_attn rows. Threads 0..255 + 256..511 handle 2 rows at a time.
  // Per-thread column range fixed -> precompute global-hit bitmask once.
  {
    int rp = tid >> 8;            // 0/1: which of the row pair
    int c0 = (tid & 255) * 4;     // fixed 4-col range
    unsigned gm = 0;
#pragma unroll
    for (int g = 0; g < NG; ++g) {
      int gc = gidx_s[g];
      if (gval_s[g] > 0.f && gc >= c0 && gc < c0 + 4) gm |= (1u << g);
    }
#pragma unroll 2
    for (int rr = 0; rr < 16; ++rr) {
      int r = rr * 2 + rp;
      int t_abs = t0 + r;
      int left = (t_abs - WND > 0) ? (t_abs - WND) : 0;
      int tmp = t_abs + WND + 1; if (tmp > T_) tmp = T_;
      int wl = tmp - left;
      float rf = rowfac_s[r];
      f32x4 o = {0.f, 0.f, 0.f, 0.f};
      int jj0 = c0 - left;
      if (jj0 > -4 && jj0 < wl) {
#pragma unroll
        for (int e = 0; e < 4; ++e) {
          int jj = jj0 + e;
          if (jj >= 0 && jj < wl) o[e] = Sw[r][jj] * rf;
        }
      }
      if (gm) {
        unsigned mm = gm;
        while (mm) {
          int g = __ffs(mm) - 1; mm &= mm - 1;
          int e = gidx_s[g] - c0;
          o[e] += Sw[r][KSZ + g] * rf;
        }
      }
      float* dst = fa + (((size_t)(b * H_ + h) * T_) + t_abs) * T_ + c0;
      *(f32x4*)dst = o;
    }
  }
}

extern "C" void kernel_launch(void* const* d_in, const int* in_sizes, int n_in,
                              void* d_out, int out_size, void* d_ws, size_t ws_size,
                              hipStream_t stream) {
  const float* x   = (const float*)d_in[0];
  const int* gmask = (const int*)d_in[1];
  const float* wq  = (const float*)d_in[2];
  const float* wk  = (const float*)d_in[3];
  const float* wv  = (const float*)d_in[4];
  const float* wo  = (const float*)d_in[5];

  char* ws = (char*)d_ws;
  unsigned short* bfarena = (unsigned short*)ws;
  unsigned short* xb  = bfarena;
  unsigned short* wqb = bfarena + 2 * 1048576;
  unsigned short* wkb = bfarena + 3 * 1048576;
  unsigned short* wvb = bfarena + 4 * 1048576;
  unsigned short* wob = bfarena + 5 * 1048576;
  float* qf = (float*)(ws + 12582912);
  float* kf = qf + 2097152;
  float* vf = kf + 2097152;
  unsigned short* ctxb = (unsigned short*)(vf + 2097152);
  int*   gidx = (int*)(ctxb + 2097152);
  float* gval = (float*)(gidx + 64);

  float* outp = (float*)d_out;
  float* fa   = outp + 2097152;

  cvt_kernel<<<dim3(6144), dim3(256), 0, stream>>>(x, wq, wk, wv, wo, bfarena);
  gidx_kernel<<<dim3(2), dim3(64), 0, stream>>>(gmask, gidx, gval);
  gemm128<0, 128><<<dim3(16, 8, 3), dim3(256), 0, stream>>>(xb, wqb, wkb, wvb, qf, kf, vf);
  attn_kernel<<<dim3(32, 16, 2), dim3(512), 0, stream>>>(qf, kf, vf, gidx, gval, ctxb, fa);
  gemm128<1, 64><<<dim3(32, 8, 1), dim3(256), 0, stream>>>(ctxb, wob, wob, wob, outp, outp, outp);
}

// Round 3
// 96.164 us; speedup vs baseline: 2.5255x; 1.2437x over previous
//
#include <hip/hip_runtime.h>

#define T_   1024
#define B_   2
#define H_   16
#define DH   64
#define D_   1024
#define WND  32
#define KSZ  65
#define NG   32

typedef float f32x4 __attribute__((ext_vector_type(4)));
typedef __bf16 bf16x8 __attribute__((ext_vector_type(8)));
typedef unsigned short u16x4 __attribute__((ext_vector_type(4)));

__device__ __forceinline__ unsigned short f2bf(float f) {
  unsigned u = __float_as_uint(f);
  return (unsigned short)((u + 0x7fffu + ((u >> 16) & 1u)) >> 16);
}

// ---------------- convert x, Wq, Wk, Wv, Wo (f32) -> contiguous bf16 arena ----------------
__global__ __launch_bounds__(256) void cvt_kernel(const float* __restrict__ x,
    const float* __restrict__ wq, const float* __restrict__ wk,
    const float* __restrict__ wv, const float* __restrict__ wo,
    unsigned short* __restrict__ dst) {
  int i4 = blockIdx.x * 256 + threadIdx.x;
  if (i4 >= (6 * 1048576) / 4) return;
  int idx = i4 * 4;
  int r = idx >> 20;
  const float* src; int off;
  if (r < 2)       { src = x;  off = idx; }
  else if (r == 2) { src = wq; off = idx - 2 * 1048576; }
  else if (r == 3) { src = wk; off = idx - 3 * 1048576; }
  else if (r == 4) { src = wv; off = idx - 4 * 1048576; }
  else             { src = wo; off = idx - 5 * 1048576; }
  f32x4 v = *(const f32x4*)(src + off);
  u16x4 o;
  o.x = f2bf(v[0]); o.y = f2bf(v[1]); o.z = f2bf(v[2]); o.w = f2bf(v[3]);
  *(u16x4*)(dst + idx) = o;
}

// ---------------- stable "argsort(!mask)" first NG indices: 1-wave ballot scan ----------------
__global__ void gidx_kernel(const int* __restrict__ mask, int* __restrict__ gidx,
                            float* __restrict__ gval) {
  int b = blockIdx.x;
  int lane = threadIdx.x;
  const int* mb = mask + b * T_;
  unsigned long long lanemask = (1ull << lane) - 1ull;
  int base = 0;
  for (int c = 0; c < 16; ++c) {
    int t = c * 64 + lane;
    bool m = mb[t] != 0;
    unsigned long long bal = __ballot(m);
    int rank = __popcll(bal & lanemask);
    if (m && base + rank < NG) { gidx[b * NG + base + rank] = t; gval[b * NG + base + rank] = 1.f; }
    base += __popcll(bal);
    if (base >= NG) break;
  }
  int start = base < NG ? base : NG;
  if (start < NG) {
    base = start;
    for (int c = 0; c < 16; ++c) {
      int t = c * 64 + lane;
      bool m = mb[t] == 0;
      unsigned long long bal = __ballot(m);
      int rank = __popcll(bal & lanemask);
      if (m && base + rank < NG) { gidx[b * NG + base + rank] = t; gval[b * NG + base + rank] = 0.f; }
      base += __popcll(bal);
      if (base >= NG) break;
    }
  }
}

// ---------------- bf16 MFMA GEMM: C = A (MxK) * B^T (NxK), K=1024, BN=128 ----------------
// MODE 0: z in {0:Q,1:K} -> bf16 [b,h,t,d]; z==2: V -> bf16 TRANSPOSED [b,h,d,t].
// MODE 1: C = f32 row-major [M][1024].
template<int MODE, int BM>
__global__ __launch_bounds__(256) void gemm128(const unsigned short* __restrict__ A,
    const unsigned short* __restrict__ B0, const unsigned short* __restrict__ B1,
    const unsigned short* __restrict__ B2,
    void* __restrict__ C0v, void* __restrict__ C1v, void* __restrict__ C2v) {
  constexpr int K = 1024;
  constexpr int FM = BM / 32;
  constexpr int ACH = BM * 8 / 256;
  constexpr int WM = BM / 2;
  __shared__ __attribute__((aligned(16))) unsigned short As[BM * 64];
  __shared__ __attribute__((aligned(16))) unsigned short Bs[128 * 64];

  int m0 = blockIdx.x * BM, n0 = blockIdx.y * 128;
  int zz = (MODE == 0) ? blockIdx.z : 0;
  const unsigned short* Bm;
  if (MODE == 0) Bm = (zz == 0) ? B0 : ((zz == 1) ? B1 : B2);
  else Bm = B0;

  int tid = threadIdx.x;
  int w = tid >> 6, l = tid & 63;
  int wr = w >> 1, wc = w & 1;
  int lr = l & 15, kg = l >> 4;

  f32x4 acc[FM][4] = {};

  for (int kt = 0; kt < K; kt += 64) {
    __syncthreads();
#pragma unroll
    for (int i = 0; i < ACH; ++i) {
      int ci = tid + 256 * i;
      int row = ci >> 3, c8 = ci & 7;
      *(bf16x8*)&As[row * 64 + ((c8 ^ (row & 7)) * 8)] =
          *(const bf16x8*)&A[(size_t)(m0 + row) * K + kt + c8 * 8];
    }
#pragma unroll
    for (int i = 0; i < 4; ++i) {
      int ci = tid + 256 * i;
      int row = ci >> 3, c8 = ci & 7;
      *(bf16x8*)&Bs[row * 64 + ((c8 ^ (row & 7)) * 8)] =
          *(const bf16x8*)&Bm[(size_t)(n0 + row) * K + kt + c8 * 8];
    }
    __syncthreads();
#pragma unroll
    for (int kk = 0; kk < 2; ++kk) {
      int c8 = kk * 4 + kg;
      bf16x8 af[FM], bfr[4];
#pragma unroll
      for (int mi = 0; mi < FM; ++mi) {
        int row = wr * WM + mi * 16 + lr;
        af[mi] = *(bf16x8*)&As[row * 64 + ((c8 ^ (row & 7)) * 8)];
      }
#pragma unroll
      for (int ni = 0; ni < 4; ++ni) {
        int row = wc * 64 + ni * 16 + lr;
        bfr[ni] = *(bf16x8*)&Bs[row * 64 + ((c8 ^ (row & 7)) * 8)];
      }
#pragma unroll
      for (int mi = 0; mi < FM; ++mi)
#pragma unroll
        for (int ni = 0; ni < 4; ++ni)
          acc[mi][ni] = __builtin_amdgcn_mfma_f32_16x16x32_bf16(af[mi], bfr[ni], acc[mi][ni], 0, 0, 0);
    }
  }

#pragma unroll
  for (int mi = 0; mi < FM; ++mi) {
#pragma unroll
    for (int ni = 0; ni < 4; ++ni) {
      int mbase = m0 + wr * WM + mi * 16 + (l >> 4) * 4;
      int n = n0 + wc * 64 + ni * 16 + (l & 15);
      if (MODE == 0) {
        unsigned short* C = (unsigned short*)((zz == 0) ? C0v : ((zz == 1) ? C1v : C2v));
        int b = mbase >> 10, t = mbase & 1023, h = n >> 6, d = n & 63;
        if (zz < 2) {
#pragma unroll
          for (int r = 0; r < 4; ++r)
            C[(((size_t)(b * H_ + h) * T_) + t + r) * DH + d] = f2bf(acc[mi][ni][r]);
        } else {
          u16x4 st;
          st.x = f2bf(acc[mi][ni][0]); st.y = f2bf(acc[mi][ni][1]);
          st.z = f2bf(acc[mi][ni][2]); st.w = f2bf(acc[mi][ni][3]);
          *(u16x4*)&C[(((size_t)(b * H_ + h) * DH) + d) * T_ + t] = st;
        }
      } else {
        float* C = (float*)C0v;
#pragma unroll
        for (int r = 0; r < 4; ++r)
          C[(size_t)(mbase + r) * 1024 + n] = acc[mi][ni][r];
      }
    }
  }
}

// ---------------- attention core: MFMA scores + MFMA PV, dual softmax, full_attn ----------------
__global__ __launch_bounds__(512, 4) void attn_kernel(
    const unsigned short* __restrict__ qg, const unsigned short* __restrict__ kg_,
    const unsigned short* __restrict__ vg,
    const int* __restrict__ gidx_g, const float* __restrict__ gval_g,
    unsigned short* __restrict__ ctxb, float* __restrict__ fa) {
  int tid = threadIdx.x;
  int t0 = blockIdx.x * 32;
  int h = blockIdx.y, b = blockIdx.z;
  int lane = tid & 63, wv = tid >> 6;

  __shared__ __attribute__((aligned(16))) unsigned short QbL[32 * 64];    // swz [t][d]
  __shared__ __attribute__((aligned(16))) unsigned short KbL[128 * 64];   // swz [r][d]
  __shared__ __attribute__((aligned(16))) unsigned short VtL[64 * 128];   // swz [d][r]
  __shared__ __attribute__((aligned(16))) unsigned short WbL[32 * 128];   // swz [t][r] bf16 weights
  __shared__ __attribute__((aligned(16))) float Sf[32][132];
  __shared__ float m_out_s[32], invdo_s[32], rowfac_s[32];
  __shared__ int   gidx_s[32];
  __shared__ float gval_s[32];

  if (tid < 32) { gidx_s[tid] = gidx_g[b * NG + tid]; gval_s[tid] = gval_g[b * NG + tid]; }
  // zero Wb (8192B)
  ((unsigned long long*)WbL)[tid] = 0ull;
  ((unsigned long long*)WbL)[tid + 512] = 0ull;
  __syncthreads();

  const unsigned short* qbh = qg + (size_t)(b * H_ + h) * T_ * DH;
  const unsigned short* kbh = kg_ + (size_t)(b * H_ + h) * T_ * DH;
  const unsigned short* vbh = vg + (size_t)(b * H_ + h) * DH * T_;  // [d][t]

  // ---- stage Q (256 chunks) ----
  if (tid < 256) {
    int r = tid >> 3, c8 = tid & 7;
    bf16x8 v = *(const bf16x8*)(qbh + (t0 + r) * 64 + c8 * 8);
    *(bf16x8*)((char*)QbL + ((r * 128 + c8 * 16) ^ ((r & 7) << 4))) = v;
  }
  // ---- stage K: window rows 0..95, globals rows 96..127 (1024 chunks) ----
#pragma unroll
  for (int it = 0; it < 2; ++it) {
    int fi = tid + it * 512;
    int r = fi >> 3, c8 = fi & 7;
    int col; bool valid;
    if (r < 96) { col = t0 - 32 + r; valid = (col >= 0 && col < T_); }
    else { int g = r - 96; valid = gval_s[g] > 0.f; col = valid ? gidx_s[g] : 0; }
    bf16x8 v = {};
    if (valid) v = *(const bf16x8*)(kbh + col * 64 + c8 * 8);
    *(bf16x8*)((char*)KbL + ((r * 128 + c8 * 16) ^ ((r & 7) << 4))) = v;
  }
  // ---- stage V^T window cols 0..95 (768 chunks of 8 t) ----
#pragma unroll
  for (int it = 0; it < 2; ++it) {
    int fi = tid + it * 512;
    if (fi < 768) {
      int d = fi / 12, rc = fi % 12;
      int cb = t0 - 32 + rc * 8;
      bf16x8 v = {};
      if (cb >= 0 && cb < T_) v = *(const bf16x8*)(vbh + d * T_ + cb);
      *(bf16x8*)((char*)VtL + ((d * 256 + rc * 16) ^ ((d & 7) << 4))) = v;
    }
  }
  // ---- stage V^T global cols 96..127 (2048 scalars) ----
#pragma unroll
  for (int it = 0; it < 4; ++it) {
    int fi = tid + it * 512;
    int d = fi >> 5, g = fi & 31;
    unsigned short v = 0;
    if (gval_s[g] > 0.f) v = vbh[d * T_ + gidx_s[g]];
    *(unsigned short*)((char*)VtL + ((d * 256 + (96 + g) * 2) ^ ((d & 7) << 4))) = v;
  }
  __syncthreads();

  // ---- phase 1: S(32x128) = Q·K^T via MFMA; Sf = scaled scores ----
  {
    int mt = wv & 1, nq = wv >> 1;
    int lr = lane & 15, kgl = lane >> 4;
    int arow = mt * 16 + lr;
    f32x4 acc0 = {}, acc1 = {};
#pragma unroll
    for (int s = 0; s < 2; ++s) {
      int c = s * 4 + kgl;
      bf16x8 a = *(bf16x8*)((char*)QbL + ((arow * 128 + c * 16) ^ ((arow & 7) << 4)));
      int br0 = nq * 32 + lr, br1 = nq * 32 + 16 + lr;
      bf16x8 b0 = *(bf16x8*)((char*)KbL + ((br0 * 128 + c * 16) ^ ((br0 & 7) << 4)));
      bf16x8 b1 = *(bf16x8*)((char*)KbL + ((br1 * 128 + c * 16) ^ ((br1 & 7) << 4)));
      acc0 = __builtin_amdgcn_mfma_f32_16x16x32_bf16(a, b0, acc0, 0, 0, 0);
      acc1 = __builtin_amdgcn_mfma_f32_16x16x32_bf16(a, b1, acc1, 0, 0, 0);
    }
    int orow = mt * 16 + (lane >> 4) * 4;
#pragma unroll
    for (int i = 0; i < 4; ++i) {
      Sf[orow + i][nq * 32 + lr] = acc0[i] * 0.125f;
      Sf[orow + i][nq * 32 + 16 + lr] = acc1[i] * 0.125f;
    }
  }
  __syncthreads();

  // ---- phase 2: per-row stats for both softmaxes (16 lanes/row) ----
  {
    int r = tid >> 4, lg = tid & 15;
    int t_abs = t0 + r;
    int left = (t_abs - WND > 0) ? (t_abs - WND) : 0;
    int tmp = t_abs + WND + 1; if (tmp > T_) tmp = T_;
    int wl = tmp - left;
    float sv[8]; bool vld[8], vdd[8];
#pragma unroll
    for (int ii = 0; ii < 8; ++ii) {
      int c = lg + ii * 16;
      bool loc = (c >= r && c <= r + 64);
      bool glob = (c >= 96);
      float s = Sf[r][c];
      if (glob && !(gval_s[c - 96] > 0.f)) s = -1e9f;
      vld[ii] = loc || glob;
      vdd[ii] = loc ? ((c - r) < wl) : glob;
      sv[ii] = s;
    }
    float mo = -1e30f, md = -1e30f;
#pragma unroll
    for (int ii = 0; ii < 8; ++ii) {
      if (vld[ii]) mo = fmaxf(mo, sv[ii]);
      if (vdd[ii]) md = fmaxf(md, sv[ii]);
    }
#pragma unroll
    for (int o = 1; o < 16; o <<= 1) {
      mo = fmaxf(mo, __shfl_xor(mo, o, 16));
      md = fmaxf(md, __shfl_xor(md, o, 16));
    }
    float eo = 0.f, ed = 0.f;
#pragma unroll
    for (int ii = 0; ii < 8; ++ii) {
      if (vld[ii]) eo += __expf(sv[ii] - mo);
      if (vdd[ii]) ed += __expf(sv[ii] - md);
    }
#pragma unroll
    for (int o = 1; o < 16; o <<= 1) {
      eo += __shfl_xor(eo, o, 16);
      ed += __shfl_xor(ed, o, 16);
    }
    if (lg == 0) {
      m_out_s[r] = mo;
      invdo_s[r] = 1.f / eo;
      rowfac_s[r] = (eo / ed) * __expf(mo - md);
    }
  }
  __syncthreads();

  // ---- phase 2b: scores -> out-path weights (f32 in Sf, bf16 in Wb) ----
  for (int idx = tid; idx < 32 * 97; idx += 512) {
    int t = idx / 97;
    int j = idx - t * 97;
    int cc = (j < KSZ) ? (t + j) : (j + 31);
    float s = Sf[t][cc];
    float wgt = __expf(s - m_out_s[t]) * invdo_s[t];
    Sf[t][cc] = wgt;
    *(unsigned short*)((char*)WbL + ((t * 256 + cc * 2) ^ ((t & 7) << 4))) = f2bf(wgt);
  }
  __syncthreads();

  // ---- phase 3: ctx^T(64x32) = V^T · W^T via MFMA ----
  {
    int mt = wv >> 1, nt = wv & 1;
    int lr = lane & 15, kgl = lane >> 4;
    int arow = mt * 16 + lr;   // d
    int brow = nt * 16 + lr;   // t
    f32x4 acc = {};
#pragma unroll
    for (int s = 0; s < 4; ++s) {
      int c = s * 4 + kgl;
      bf16x8 a = *(bf16x8*)((char*)VtL + ((arow * 256 + c * 16) ^ ((arow & 7) << 4)));
      bf16x8 bb = *(bf16x8*)((char*)WbL + ((brow * 256 + c * 16) ^ ((brow & 7) << 4)));
      acc = __builtin_amdgcn_mfma_f32_16x16x32_bf16(a, bb, acc, 0, 0, 0);
    }
    int t = nt * 16 + lr;
    int dbase = mt * 16 + (lane >> 4) * 4;
    u16x4 st;
    st.x = f2bf(acc[0]); st.y = f2bf(acc[1]); st.z = f2bf(acc[2]); st.w = f2bf(acc[3]);
    *(u16x4*)(ctxb + ((size_t)(b * T_ + t0 + t)) * D_ + h * DH + dbase) = st;
  }

  // ---- phase 4: dense full_attn rows ----
  {
    int rp = tid >> 8;
    int c0 = (tid & 255) * 4;
    unsigned gm = 0;
#pragma unroll
    for (int g = 0; g < NG; ++g) {
      int gc = gidx_s[g];
      if (gval_s[g] > 0.f && gc >= c0 && gc < c0 + 4) gm |= (1u << g);
    }
#pragma unroll 2
    for (int rr = 0; rr < 16; ++rr) {
      int r = rr * 2 + rp;
      int t_abs = t0 + r;
      int left = (t_abs - WND > 0) ? (t_abs - WND) : 0;
      int tmp = t_abs + WND + 1; if (tmp > T_) tmp = T_;
      int wl = tmp - left;
      float rf = rowfac_s[r];
      f32x4 o = {0.f, 0.f, 0.f, 0.f};
      int jj0 = c0 - left;
      if (jj0 > -4 && jj0 < wl) {
#pragma unroll
        for (int e = 0; e < 4; ++e) {
          int jj = jj0 + e;
          if (jj >= 0 && jj < wl) o[e] = Sf[r][r + jj] * rf;
        }
      }
      if (gm) {
        unsigned mm = gm;
        while (mm) {
          int g = __ffs(mm) - 1; mm &= mm - 1;
          int e = gidx_s[g] - c0;
          o[e] += Sf[r][96 + g] * rf;
        }
      }
      float* dst = fa + (((size_t)(b * H_ + h) * T_) + t_abs) * T_ + c0;
      *(f32x4*)dst = o;
    }
  }
}

extern "C" void kernel_launch(void* const* d_in, const int* in_sizes, int n_in,
                              void* d_out, int out_size, void* d_ws, size_t ws_size,
                              hipStream_t stream) {
  const float* x   = (const float*)d_in[0];
  const int* gmask = (const int*)d_in[1];
  const float* wq  = (const float*)d_in[2];
  const float* wk  = (const float*)d_in[3];
  const float* wv  = (const float*)d_in[4];
  const float* wo  = (const float*)d_in[5];

  char* ws = (char*)d_ws;
  unsigned short* bfarena = (unsigned short*)ws;   // 6M u16
  unsigned short* xb  = bfarena;
  unsigned short* wqb = bfarena + 2 * 1048576;
  unsigned short* wkb = bfarena + 3 * 1048576;
  unsigned short* wvb = bfarena + 4 * 1048576;
  unsigned short* wob = bfarena + 5 * 1048576;
  unsigned short* qb  = bfarena + 6 * 1048576;     // [b,h,t,d] bf16, 2M
  unsigned short* kb  = qb + 2 * 1048576;          // [b,h,t,d]
  unsigned short* vtb = kb + 2 * 1048576;          // [b,h,d,t]
  unsigned short* ctxb = vtb + 2 * 1048576;        // [b*T+t][1024]
  int*   gidx = (int*)(ctxb + 2 * 1048576);
  float* gval = (float*)(gidx + 64);

  float* outp = (float*)d_out;
  float* fa   = outp + 2097152;

  cvt_kernel<<<dim3(6144), dim3(256), 0, stream>>>(x, wq, wk, wv, wo, bfarena);
  gidx_kernel<<<dim3(2), dim3(64), 0, stream>>>(gmask, gidx, gval);
  gemm128<0, 128><<<dim3(16, 8, 3), dim3(256), 0, stream>>>(xb, wqb, wkb, wvb, qb, kb, vtb);
  attn_kernel<<<dim3(32, 16, 2), dim3(512), 0, stream>>>(qb, kb, vtb, gidx, gval, ctxb, fa);
  gemm128<1, 64><<<dim3(32, 8, 1), dim3(256), 0, stream>>>(ctxb, wob, wob, wob, outp, outp, outp);
}

// Round 4
// 95.022 us; speedup vs baseline: 2.5558x; 1.0120x over previous
//
#include <hip/hip_runtime.h>

#define T_   1024
#define B_   2
#define H_   16
#define DH   64
#define D_   1024
#define WND  32
#define KSZ  65
#define NG   32

typedef float f32x4 __attribute__((ext_vector_type(4)));
typedef __bf16 bf16x8 __attribute__((ext_vector_type(8)));
typedef __bf16 bf16x4 __attribute__((ext_vector_type(4)));
typedef unsigned short u16x4 __attribute__((ext_vector_type(4)));

__device__ __forceinline__ unsigned short f2bf(float f) {
  unsigned u = __float_as_uint(f);
  return (unsigned short)((u + 0x7fffu + ((u >> 16) & 1u)) >> 16);
}

template<bool F32>
__device__ __forceinline__ bf16x8 load_cvt8(const char* p) {
  if constexpr (F32) {
    f32x4 a = *(const f32x4*)p;
    f32x4 b = *(const f32x4*)(p + 16);
    bf16x8 r;
    r[0] = (__bf16)a[0]; r[1] = (__bf16)a[1]; r[2] = (__bf16)a[2]; r[3] = (__bf16)a[3];
    r[4] = (__bf16)b[0]; r[5] = (__bf16)b[1]; r[6] = (__bf16)b[2]; r[7] = (__bf16)b[3];
    return r;
  } else {
    return *(const bf16x8*)p;
  }
}

// ---------------- bf16 MFMA GEMM: C = A (MxK) * B^T (NxK), K=1024, BN=128 ----------------
// MODE 0: z in {0:Q,1:K} -> bf16 row-major [M][1024]; z==2: V -> bf16 TRANSPOSED [b,h,d,t]
//         (via LDS-transposed epilogue). blockIdx.x==16 side-block runs the gidx ballot scan.
// MODE 1: C = f32 row-major [M][1024].
// AF32/BF32: source operands are f32, converted to bf16 during staging (fused cvt).
template<int MODE, int BM, bool AF32, bool BF32>
__global__ __launch_bounds__(256) void gemm128(
    const void* __restrict__ A,
    const void* __restrict__ B0, const void* __restrict__ B1, const void* __restrict__ B2,
    void* __restrict__ C0v, void* __restrict__ C1v, void* __restrict__ C2v,
    const int* __restrict__ mask, int* __restrict__ gidxo, float* __restrict__ gvalo) {
  constexpr int K = 1024;
  constexpr int FM = BM / 32;
  constexpr int ACH = BM * 8 / 256;
  constexpr int WM = BM / 2;
  constexpr int AE = AF32 ? 4 : 2, BE = BF32 ? 4 : 2;

  // ---- gidx side-block (stable argsort(!mask) first NG) ----
  if (MODE == 0 && blockIdx.x == 16) {
    if (blockIdx.y == 0 && blockIdx.z == 0 && threadIdx.x < 128) {
      int b = threadIdx.x >> 6, lane = threadIdx.x & 63;
      const int* mb = mask + b * T_;
      unsigned long long lanemask = (1ull << lane) - 1ull;
      int base = 0;
      for (int c = 0; c < 16 && base < NG; ++c) {
        int t = c * 64 + lane;
        bool m = mb[t] != 0;
        unsigned long long bal = __ballot(m);
        int rank = __popcll(bal & lanemask);
        if (m && base + rank < NG) { gidxo[b*NG+base+rank] = t; gvalo[b*NG+base+rank] = 1.f; }
        base += __popcll(bal);
      }
      if (base < NG) {
        for (int c = 0; c < 16 && base < NG; ++c) {
          int t = c * 64 + lane;
          bool m = mb[t] == 0;
          unsigned long long bal = __ballot(m);
          int rank = __popcll(bal & lanemask);
          if (m && base + rank < NG) { gidxo[b*NG+base+rank] = t; gvalo[b*NG+base+rank] = 0.f; }
          base += __popcll(bal);
        }
      }
    }
    return;
  }

  __shared__ __attribute__((aligned(16))) unsigned short SMEM[BM * 64 + 128 * 64];
  unsigned short* As = SMEM;
  unsigned short* Bs = SMEM + BM * 64;

  int m0 = blockIdx.x * BM, n0 = blockIdx.y * 128;
  int zz = (MODE == 0) ? blockIdx.z : 0;
  const char* Ab = (const char*)A;
  const char* Bb = (const char*)((MODE == 0) ? (zz == 0 ? B0 : (zz == 1 ? B1 : B2)) : B0);

  int tid = threadIdx.x;
  int w = tid >> 6, l = tid & 63;
  int wr = w >> 1, wc = w & 1;
  int lr = l & 15, kg = l >> 4;

  f32x4 acc[FM][4] = {};

  for (int kt = 0; kt < K; kt += 64) {
    __syncthreads();
#pragma unroll
    for (int i = 0; i < ACH; ++i) {
      int ci = tid + 256 * i;
      int row = ci >> 3, c8 = ci & 7;
      *(bf16x8*)&As[row * 64 + ((c8 ^ (row & 7)) * 8)] =
          load_cvt8<AF32>(Ab + ((size_t)(m0 + row) * K + kt + c8 * 8) * AE);
    }
#pragma unroll
    for (int i = 0; i < 4; ++i) {
      int ci = tid + 256 * i;
      int row = ci >> 3, c8 = ci & 7;
      *(bf16x8*)&Bs[row * 64 + ((c8 ^ (row & 7)) * 8)] =
          load_cvt8<BF32>(Bb + ((size_t)(n0 + row) * K + kt + c8 * 8) * BE);
    }
    __syncthreads();
#pragma unroll
    for (int kk = 0; kk < 2; ++kk) {
      int c8 = kk * 4 + kg;
      bf16x8 af[FM], bfr[4];
#pragma unroll
      for (int mi = 0; mi < FM; ++mi) {
        int row = wr * WM + mi * 16 + lr;
        af[mi] = *(bf16x8*)&As[row * 64 + ((c8 ^ (row & 7)) * 8)];
      }
#pragma unroll
      for (int ni = 0; ni < 4; ++ni) {
        int row = wc * 64 + ni * 16 + lr;
        bfr[ni] = *(bf16x8*)&Bs[row * 64 + ((c8 ^ (row & 7)) * 8)];
      }
#pragma unroll
      for (int mi = 0; mi < FM; ++mi)
#pragma unroll
        for (int ni = 0; ni < 4; ++ni)
          acc[mi][ni] = __builtin_amdgcn_mfma_f32_16x16x32_bf16(af[mi], bfr[ni], acc[mi][ni], 0, 0, 0);
    }
  }

  if (MODE == 1) {
    float* C = (float*)C0v;
#pragma unroll
    for (int mi = 0; mi < FM; ++mi)
#pragma unroll
      for (int ni = 0; ni < 4; ++ni) {
        int mbase = m0 + wr * WM + mi * 16 + (l >> 4) * 4;
        int n = n0 + wc * 64 + ni * 16 + lr;
#pragma unroll
        for (int r = 0; r < 4; ++r)
          C[(size_t)(mbase + r) * 1024 + n] = acc[mi][ni][r];
      }
  } else if (zz < 2) {
    unsigned short* C = (unsigned short*)(zz == 0 ? C0v : C1v);
#pragma unroll
    for (int mi = 0; mi < FM; ++mi)
#pragma unroll
      for (int ni = 0; ni < 4; ++ni) {
        int mbase = m0 + wr * WM + mi * 16 + (l >> 4) * 4;
        int n = n0 + wc * 64 + ni * 16 + lr;
#pragma unroll
        for (int r = 0; r < 4; ++r) {
          __bf16 v = (__bf16)acc[mi][ni][r];
          C[(size_t)(mbase + r) * 1024 + n] = *(unsigned short*)&v;
        }
      }
  } else {
    // V: LDS transpose (tile [n][m], swizzled) -> coalesced [b,h,d,t] stores
    __syncthreads();
    char* Tb = (char*)SMEM;
#pragma unroll
    for (int mi = 0; mi < FM; ++mi)
#pragma unroll
      for (int ni = 0; ni < 4; ++ni) {
        int mb2 = wr * WM + mi * 16 + (l >> 4) * 4;
        int nl = wc * 64 + ni * 16 + lr;
        bf16x4 pk;
        pk[0] = (__bf16)acc[mi][ni][0]; pk[1] = (__bf16)acc[mi][ni][1];
        pk[2] = (__bf16)acc[mi][ni][2]; pk[3] = (__bf16)acc[mi][ni][3];
        *(bf16x4*)(Tb + ((nl * 256 + mb2 * 2) ^ ((nl & 7) << 4))) = pk;
      }
    __syncthreads();
    unsigned short* C = (unsigned short*)C2v;
    int bb = m0 >> 10, tbase = m0 & 1023;
#pragma unroll
    for (int it = 0; it < 8; ++it) {
      int ci = tid + 256 * it;
      int dl = ci >> 4, tc = ci & 15;
      bf16x8 v = *(bf16x8*)(Tb + ((dl * 256 + tc * 16) ^ ((dl & 7) << 4)));
      int n = n0 + dl, hh = n >> 6, dd = n & 63;
      *(bf16x8*)&C[((size_t)(bb * H_ + hh) * DH + dd) * T_ + tbase + tc * 8] = v;
    }
  }
}

// ---------------- attention core: MFMA scores + MFMA PV, dual softmax, full_attn ----------------
// q,k: bf16 row-major [b*T][1024] (col = h*64+d). v: bf16 [b,h,d,t].
__global__ __launch_bounds__(512, 4) void attn_kernel(
    const unsigned short* __restrict__ qg, const unsigned short* __restrict__ kg_,
    const unsigned short* __restrict__ vg,
    const int* __restrict__ gidx_g, const float* __restrict__ gval_g,
    unsigned short* __restrict__ ctxb, float* __restrict__ fa) {
  int tid = threadIdx.x;
  int t0 = blockIdx.x * 32;
  int h = blockIdx.y, b = blockIdx.z;
  int lane = tid & 63, wv = tid >> 6;

  __shared__ __attribute__((aligned(16))) unsigned short QbL[32 * 64];    // swz [t][d]
  __shared__ __attribute__((aligned(16))) unsigned short KbL[128 * 64];   // swz [r][d]
  __shared__ __attribute__((aligned(16))) unsigned short VtL[64 * 128];   // swz [d][r]
  __shared__ __attribute__((aligned(16))) unsigned short WbL[32 * 128];   // swz [t][r] bf16 weights
  __shared__ __attribute__((aligned(16))) float Sf[32][132];
  __shared__ float m_out_s[32], invdo_s[32], rowfac_s[32];
  __shared__ int   gidx_s[32];
  __shared__ float gval_s[32];

  if (tid < 32) { gidx_s[tid] = gidx_g[b * NG + tid]; gval_s[tid] = gval_g[b * NG + tid]; }
  ((unsigned long long*)WbL)[tid] = 0ull;
  ((unsigned long long*)WbL)[tid + 512] = 0ull;
  __syncthreads();

  const unsigned short* qbh = qg + (size_t)(b * T_ + t0) * D_ + h * DH;
  const unsigned short* kbh = kg_ + (size_t)(b * T_) * D_ + h * DH;
  const unsigned short* vbh = vg + (size_t)(b * H_ + h) * DH * T_;  // [d][t]

  // ---- stage Q (256 chunks) ----
  if (tid < 256) {
    int r = tid >> 3, c8 = tid & 7;
    bf16x8 v = *(const bf16x8*)(qbh + (size_t)r * D_ + c8 * 8);
    *(bf16x8*)((char*)QbL + ((r * 128 + c8 * 16) ^ ((r & 7) << 4))) = v;
  }
  // ---- stage K: window rows 0..95, globals rows 96..127 (1024 chunks) ----
#pragma unroll
  for (int it = 0; it < 2; ++it) {
    int fi = tid + it * 512;
    int r = fi >> 3, c8 = fi & 7;
    int col; bool valid;
    if (r < 96) { col = t0 - 32 + r; valid = (col >= 0 && col < T_); }
    else { int g = r - 96; valid = gval_s[g] > 0.f; col = valid ? gidx_s[g] : 0; }
    bf16x8 v = {};
    if (valid) v = *(const bf16x8*)(kbh + (size_t)col * D_ + c8 * 8);
    *(bf16x8*)((char*)KbL + ((r * 128 + c8 * 16) ^ ((r & 7) << 4))) = v;
  }
  // ---- stage V^T window cols 0..95 (768 chunks of 8 t) ----
#pragma unroll
  for (int it = 0; it < 2; ++it) {
    int fi = tid + it * 512;
    if (fi < 768) {
      int d = fi / 12, rc = fi % 12;
      int cb = t0 - 32 + rc * 8;
      bf16x8 v = {};
      if (cb >= 0 && cb < T_) v = *(const bf16x8*)(vbh + d * T_ + cb);
      *(bf16x8*)((char*)VtL + ((d * 256 + rc * 16) ^ ((d & 7) << 4))) = v;
    }
  }
  // ---- stage V^T global cols 96..127 (2048 scalars) ----
#pragma unroll
  for (int it = 0; it < 4; ++it) {
    int fi = tid + it * 512;
    int d = fi >> 5, g = fi & 31;
    unsigned short v = 0;
    if (gval_s[g] > 0.f) v = vbh[d * T_ + gidx_s[g]];
    *(unsigned short*)((char*)VtL + ((d * 256 + (96 + g) * 2) ^ ((d & 7) << 4))) = v;
  }
  __syncthreads();

  // ---- phase 1: S(32x128) = Q·K^T via MFMA ----
  {
    int mt = wv & 1, nq = wv >> 1;
    int lrr = lane & 15, kgl = lane >> 4;
    int arow = mt * 16 + lrr;
    f32x4 acc0 = {}, acc1 = {};
#pragma unroll
    for (int s = 0; s < 2; ++s) {
      int c = s * 4 + kgl;
      bf16x8 a = *(bf16x8*)((char*)QbL + ((arow * 128 + c * 16) ^ ((arow & 7) << 4)));
      int br0 = nq * 32 + lrr, br1 = nq * 32 + 16 + lrr;
      bf16x8 b0 = *(bf16x8*)((char*)KbL + ((br0 * 128 + c * 16) ^ ((br0 & 7) << 4)));
      bf16x8 b1 = *(bf16x8*)((char*)KbL + ((br1 * 128 + c * 16) ^ ((br1 & 7) << 4)));
      acc0 = __builtin_amdgcn_mfma_f32_16x16x32_bf16(a, b0, acc0, 0, 0, 0);
      acc1 = __builtin_amdgcn_mfma_f32_16x16x32_bf16(a, b1, acc1, 0, 0, 0);
    }
    int orow = mt * 16 + (lane >> 4) * 4;
#pragma unroll
    for (int i = 0; i < 4; ++i) {
      Sf[orow + i][nq * 32 + lrr] = acc0[i] * 0.125f;
      Sf[orow + i][nq * 32 + 16 + lrr] = acc1[i] * 0.125f;
    }
  }
  __syncthreads();

  // ---- phase 2: per-row stats for both softmaxes (16 lanes/row) ----
  {
    int r = tid >> 4, lg = tid & 15;
    int t_abs = t0 + r;
    int left = (t_abs - WND > 0) ? (t_abs - WND) : 0;
    int tmp = t_abs + WND + 1; if (tmp > T_) tmp = T_;
    int wl = tmp - left;
    float sv[8]; bool vld[8], vdd[8];
#pragma unroll
    for (int ii = 0; ii < 8; ++ii) {
      int c = lg + ii * 16;
      bool loc = (c >= r && c <= r + 64);
      bool glob = (c >= 96);
      float s = Sf[r][c];
      if (glob && !(gval_s[c - 96] > 0.f)) s = -1e9f;
      vld[ii] = loc || glob;
      vdd[ii] = loc ? ((c - r) < wl) : glob;
      sv[ii] = s;
    }
    float mo = -1e30f, md = -1e30f;
#pragma unroll
    for (int ii = 0; ii < 8; ++ii) {
      if (vld[ii]) mo = fmaxf(mo, sv[ii]);
      if (vdd[ii]) md = fmaxf(md, sv[ii]);
    }
#pragma unroll
    for (int o = 1; o < 16; o <<= 1) {
      mo = fmaxf(mo, __shfl_xor(mo, o, 16));
      md = fmaxf(md, __shfl_xor(md, o, 16));
    }
    float eo = 0.f, ed = 0.f;
#pragma unroll
    for (int ii = 0; ii < 8; ++ii) {
      if (vld[ii]) eo += __expf(sv[ii] - mo);
      if (vdd[ii]) ed += __expf(sv[ii] - md);
    }
#pragma unroll
    for (int o = 1; o < 16; o <<= 1) {
      eo += __shfl_xor(eo, o, 16);
      ed += __shfl_xor(ed, o, 16);
    }
    if (lg == 0) {
      m_out_s[r] = mo;
      invdo_s[r] = 1.f / eo;
      rowfac_s[r] = (eo / ed) * __expf(mo - md);
    }
  }
  __syncthreads();

  // ---- phase 2b: scores -> out-path weights (f32 in Sf, bf16 in Wb) ----
  for (int idx = tid; idx < 32 * 97; idx += 512) {
    int t = idx / 97;
    int j = idx - t * 97;
    int cc = (j < KSZ) ? (t + j) : (j + 31);
    float s = Sf[t][cc];
    float wgt = __expf(s - m_out_s[t]) * invdo_s[t];
    Sf[t][cc] = wgt;
    *(unsigned short*)((char*)WbL + ((t * 256 + cc * 2) ^ ((t & 7) << 4))) = f2bf(wgt);
  }
  __syncthreads();

  // ---- phase 3: ctx^T(64x32) = V^T · W^T via MFMA ----
  {
    int mt = wv >> 1, nt = wv & 1;
    int lrr = lane & 15, kgl = lane >> 4;
    int arow = mt * 16 + lrr;   // d
    int brow = nt * 16 + lrr;   // t
    f32x4 acc = {};
#pragma unroll
    for (int s = 0; s < 4; ++s) {
      int c = s * 4 + kgl;
      bf16x8 a = *(bf16x8*)((char*)VtL + ((arow * 256 + c * 16) ^ ((arow & 7) << 4)));
      bf16x8 bb = *(bf16x8*)((char*)WbL + ((brow * 256 + c * 16) ^ ((brow & 7) << 4)));
      acc = __builtin_amdgcn_mfma_f32_16x16x32_bf16(a, bb, acc, 0, 0, 0);
    }
    int t = nt * 16 + lrr;
    int dbase = mt * 16 + (lane >> 4) * 4;
    u16x4 st;
    st.x = f2bf(acc[0]); st.y = f2bf(acc[1]); st.z = f2bf(acc[2]); st.w = f2bf(acc[3]);
    *(u16x4*)(ctxb + ((size_t)(b * T_ + t0 + t)) * D_ + h * DH + dbase) = st;
  }

  // ---- phase 4: dense full_attn rows ----
  {
    int rp = tid >> 8;
    int c0 = (tid & 255) * 4;
    unsigned gm = 0;
#pragma unroll
    for (int g = 0; g < NG; ++g) {
      int gc = gidx_s[g];
      if (gval_s[g] > 0.f && gc >= c0 && gc < c0 + 4) gm |= (1u << g);
    }
#pragma unroll 2
    for (int rr = 0; rr < 16; ++rr) {
      int r = rr * 2 + rp;
      int t_abs = t0 + r;
      int left = (t_abs - WND > 0) ? (t_abs - WND) : 0;
      int tmp = t_abs + WND + 1; if (tmp > T_) tmp = T_;
      int wl = tmp - left;
      float rf = rowfac_s[r];
      f32x4 o = {0.f, 0.f, 0.f, 0.f};
      int jj0 = c0 - left;
      if (jj0 > -4 && jj0 < wl) {
#pragma unroll
        for (int e = 0; e < 4; ++e) {
          int jj = jj0 + e;
          if (jj >= 0 && jj < wl) o[e] = Sf[r][r + jj] * rf;
        }
      }
      if (gm) {
        unsigned mm = gm;
        while (mm) {
          int g = __ffs(mm) - 1; mm &= mm - 1;
          int e = gidx_s[g] - c0;
          o[e] += Sf[r][96 + g] * rf;
        }
      }
      float* dst = fa + (((size_t)(b * H_ + h) * T_) + t_abs) * T_ + c0;
      *(f32x4*)dst = o;
    }
  }
}

extern "C" void kernel_launch(void* const* d_in, const int* in_sizes, int n_in,
                              void* d_out, int out_size, void* d_ws, size_t ws_size,
                              hipStream_t stream) {
  const float* x   = (const float*)d_in[0];
  const int* gmask = (const int*)d_in[1];
  const float* wq  = (const float*)d_in[2];
  const float* wk  = (const float*)d_in[3];
  const float* wv  = (const float*)d_in[4];
  const float* wo  = (const float*)d_in[5];

  char* ws = (char*)d_ws;
  unsigned short* qb   = (unsigned short*)ws;      // [2048][1024] bf16
  unsigned short* kb   = qb + 2 * 1048576;         // [2048][1024] bf16
  unsigned short* vtb  = kb + 2 * 1048576;         // [b,h,d,t] bf16
  unsigned short* ctxb = vtb + 2 * 1048576;        // [2048][1024] bf16
  int*   gidx = (int*)(ctxb + 2 * 1048576);
  float* gval = (float*)(gidx + 64);

  float* outp = (float*)d_out;
  float* fa   = outp + 2097152;

  gemm128<0, 128, true, true><<<dim3(17, 8, 3), dim3(256), 0, stream>>>(
      x, wq, wk, wv, qb, kb, vtb, gmask, gidx, gval);
  attn_kernel<<<dim3(32, 16, 2), dim3(512), 0, stream>>>(qb, kb, vtb, gidx, gval, ctxb, fa);
  gemm128<1, 64, false, true><<<dim3(32, 8, 1), dim3(256), 0, stream>>>(
      ctxb, wo, wo, wo, outp, outp, outp, nullptr, nullptr, nullptr);
}